// Round 1
// baseline (259.221 us; speedup 1.0000x reference)
//
#include <hip/hip_runtime.h>

// DPP quad_perm controls: lane <- lane^1 / lane^2 / lane^3 within each quad
#define DPP_XOR1 0xB1   // [1,0,3,2]
#define DPP_XOR2 0x4E   // [2,3,0,1]
#define DPP_XOR3 0x1B   // [3,2,1,0]

template <int CTRL>
__device__ __forceinline__ float dppf(float x) {
  return __int_as_float(__builtin_amdgcn_update_dpp(
      0, __float_as_int(x), CTRL, 0xF, 0xF, true));
}

__device__ __forceinline__ float fast_tanh(float x) {
  // tanh(x) = (e^{2x}-1)/(e^{2x}+1) = 1 - 2/(e^{2x}+1)
  float e = __expf(2.0f * x);
  float r = __builtin_amdgcn_rcpf(e + 1.0f);
  return fmaf(-2.0f, r, 1.0f);
}

// B=16384, D=2472, N=50, H=4.
// 4 lanes per row (h/k hybrid split), 256 threads/block -> 64 rows/block,
// 256 blocks -> all 256 CUs, 1 wave/SIMD.
__global__ __launch_bounds__(256) void rec_policy_kernel(
    const float* __restrict__ x,
    const float* __restrict__ Wcf1, const float* __restrict__ bcf1,
    const float* __restrict__ Wihu, const float* __restrict__ bihu,
    const float* __restrict__ Whhu, const float* __restrict__ bhhu,
    const float* __restrict__ Wfc1, const float* __restrict__ bfc1,
    const float* __restrict__ Wfc2, const float* __restrict__ bfc2,
    const float* __restrict__ Wihd, const float* __restrict__ bihd,
    const float* __restrict__ Whhd, const float* __restrict__ bhhd,
    const float* __restrict__ Wout, const float* __restrict__ bout,
    float* __restrict__ out)
{
  const int tid = threadIdx.x;
  const int l   = tid & 3;                    // lane within quad
  const int b   = blockIdx.x * 64 + (tid >> 2);
  const float* __restrict__ xr = x + (size_t)b * 2472;

  // ---------------- weight prep (all static-indexed registers) ----------------
  // Folded Wc = W_ih_up @ W_cf1  (4x16); lane l keeps columns {l, l+4, l+8, l+12}
  float wihu[4][4];
  #pragma unroll
  for (int m = 0; m < 4; ++m) {
    #pragma unroll
    for (int k = 0; k < 4; ++k) wihu[m][k] = Wihu[m * 4 + k];
  }
  float wck[4][4];   // wck[m][j] = Wc[m][l + 4j]
  #pragma unroll
  for (int m = 0; m < 4; ++m) {
    #pragma unroll
    for (int j = 0; j < 4; ++j) {
      const int c = l + 4 * j;
      wck[m][j] = wihu[m][0] * Wcf1[c]      + wihu[m][1] * Wcf1[16 + c]
                + wihu[m][2] * Wcf1[32 + c] + wihu[m][3] * Wcf1[48 + c];
    }
  }
  // total bias for lane-l output of the up cell:
  // (W_ih_up @ b_cf1)[l] + b_ih_up[l] + b_hh_up[l]
  float btot = bihu[l] + bhhu[l]
             + Wihu[l * 4 + 0] * bcf1[0] + Wihu[l * 4 + 1] * bcf1[1]
             + Wihu[l * 4 + 2] * bcf1[2] + Wihu[l * 4 + 3] * bcf1[3];
  // permuted W_hh_up row l: whhp[j] = W_hh_up[l][l^j]  (matches DPP gather order)
  float whhp[4];
  #pragma unroll
  for (int j = 0; j < 4; ++j) whhp[j] = Whhu[l * 4 + (l ^ j)];

  const bool s1 = (l & 1) != 0;
  const bool s2b = (l & 2) != 0;

  // ---------------- up scan: i = 49 .. 0 (reverse over cells) ----------------
  float h = 0.0f;
  float hup[7];

  #pragma unroll
  for (int i = 49; i >= 0; --i) {
    // lc slice for cell i: cols [7+50i, 7+50i+8) and [407+8i, 407+8i+8)
    const float* pA = xr + 7 + 50 * i + l;
    const float* pB = xr + 407 + 8 * i + l;
    float v0 = pA[0];   // lc[l]
    float v1 = pA[4];   // lc[l+4]
    float v2 = pB[0];   // lc[8+l]
    float v3 = pB[4];   // lc[12+l]

    // partials for all 4 outputs over this lane's 4 k's
    float p0 = fmaf(wck[0][0], v0, fmaf(wck[0][1], v1, fmaf(wck[0][2], v2, wck[0][3] * v3)));
    float p1 = fmaf(wck[1][0], v0, fmaf(wck[1][1], v1, fmaf(wck[1][2], v2, wck[1][3] * v3)));
    float p2 = fmaf(wck[2][0], v0, fmaf(wck[2][1], v1, fmaf(wck[2][2], v2, wck[2][3] * v3)));
    float p3 = fmaf(wck[3][0], v0, fmaf(wck[3][1], v1, fmaf(wck[3][2], v2, wck[3][3] * v3)));

    // butterfly all-reduce across the quad (DPP, pure VALU)
    p0 += dppf<DPP_XOR1>(p0); p1 += dppf<DPP_XOR1>(p1);
    p2 += dppf<DPP_XOR1>(p2); p3 += dppf<DPP_XOR1>(p3);
    p0 += dppf<DPP_XOR2>(p0); p1 += dppf<DPP_XOR2>(p1);
    p2 += dppf<DPP_XOR2>(p2); p3 += dppf<DPP_XOR2>(p3);

    // pick this lane's output sum p[l]
    float sel = s2b ? (s1 ? p3 : p2) : (s1 ? p1 : p0);

    // h-recurrence term: gather all h via quad DPP
    float g1 = dppf<DPP_XOR1>(h);
    float g2 = dppf<DPP_XOR2>(h);
    float g3 = dppf<DPP_XOR3>(h);
    float s = sel + btot;
    s = fmaf(whhp[0], h,  s);
    s = fmaf(whhp[1], g1, s);
    s = fmaf(whhp[2], g2, s);
    s = fmaf(whhp[3], g3, s);
    h = fast_tanh(s);

    if (i < 7) hup[i] = h;   // compile-time resolved (full unroll)
  }
  // h == h_last here; hup[i] = hidden after cell i for i=0..6 (lane's component)

  // ---------------- fc stage ----------------
  // t1 = tanh(cat(obs, h_last) @ W_fc1.T + b_fc1); h = tanh(t1 @ W_fc2.T + b_fc2)
  float pre1 = bfc1[l];
  #pragma unroll
  for (int k = 0; k < 7; ++k) pre1 = fmaf(Wfc1[l * 11 + k], xr[k], pre1);
  {
    float g1 = dppf<DPP_XOR1>(h);
    float g2 = dppf<DPP_XOR2>(h);
    float g3 = dppf<DPP_XOR3>(h);
    pre1 = fmaf(Wfc1[l * 11 + 7 + (l ^ 0)], h,  pre1);
    pre1 = fmaf(Wfc1[l * 11 + 7 + (l ^ 1)], g1, pre1);
    pre1 = fmaf(Wfc1[l * 11 + 7 + (l ^ 2)], g2, pre1);
    pre1 = fmaf(Wfc1[l * 11 + 7 + (l ^ 3)], g3, pre1);
  }
  float t1 = fast_tanh(pre1);
  float acc2 = bfc2[l];
  {
    float g1 = dppf<DPP_XOR1>(t1);
    float g2 = dppf<DPP_XOR2>(t1);
    float g3 = dppf<DPP_XOR3>(t1);
    acc2 = fmaf(Wfc2[l * 4 + (l ^ 0)], t1, acc2);
    acc2 = fmaf(Wfc2[l * 4 + (l ^ 1)], g1, acc2);
    acc2 = fmaf(Wfc2[l * 4 + (l ^ 2)], g2, acc2);
    acc2 = fmaf(Wfc2[l * 4 + (l ^ 3)], g3, acc2);
  }
  h = fast_tanh(acc2);

  // ---------------- down scan: t = 0..6 ----------------
  float wid[4], whd[4], wo[4];
  #pragma unroll
  for (int j = 0; j < 4; ++j) {
    wid[j] = Wihd[l * 4 + (l ^ j)];
    whd[j] = Whhd[l * 4 + (l ^ j)];
    wo[j]  = Wout[l ^ j];
  }
  const float bdn = bihd[l] + bhhd[l];
  const float wo4 = Wout[4];
  const float bo  = bout[0];

  #pragma unroll
  for (int t = 0; t < 7; ++t) {
    float g1 = dppf<DPP_XOR1>(h);
    float g2 = dppf<DPP_XOR2>(h);
    float g3 = dppf<DPP_XOR3>(h);
    // act computed from h BEFORE the cell update
    float act = fmaf(wo4, xr[7 + t], bo);
    act = fmaf(wo[0], h,  act);
    act = fmaf(wo[1], g1, act);
    act = fmaf(wo[2], g2, act);
    act = fmaf(wo[3], g3, act);
    if (l == 0) out[(size_t)b * 7 + t] = act;

    float hu = hup[t];
    float u1 = dppf<DPP_XOR1>(hu);
    float u2 = dppf<DPP_XOR2>(hu);
    float u3 = dppf<DPP_XOR3>(hu);
    float s = bdn;
    s = fmaf(wid[0], hu, s);
    s = fmaf(wid[1], u1, s);
    s = fmaf(wid[2], u2, s);
    s = fmaf(wid[3], u3, s);
    s = fmaf(whd[0], h,  s);
    s = fmaf(whd[1], g1, s);
    s = fmaf(whd[2], g2, s);
    s = fmaf(whd[3], g3, s);
    h = fast_tanh(s);
  }
}

extern "C" void kernel_launch(void* const* d_in, const int* in_sizes, int n_in,
                              void* d_out, int out_size, void* d_ws, size_t ws_size,
                              hipStream_t stream) {
  (void)in_sizes; (void)n_in; (void)d_ws; (void)ws_size; (void)out_size;
  rec_policy_kernel<<<dim3(256), dim3(256), 0, stream>>>(
      (const float*)d_in[0],
      (const float*)d_in[1],  (const float*)d_in[2],
      (const float*)d_in[3],  (const float*)d_in[4],
      (const float*)d_in[5],  (const float*)d_in[6],
      (const float*)d_in[7],  (const float*)d_in[8],
      (const float*)d_in[9],  (const float*)d_in[10],
      (const float*)d_in[11], (const float*)d_in[12],
      (const float*)d_in[13], (const float*)d_in[14],
      (const float*)d_in[15], (const float*)d_in[16],
      (float*)d_out);
}